// Round 1
// baseline (2572.444 us; speedup 1.0000x reference)
//
#include <hip/hip_runtime.h>
#include <stdint.h>

typedef __attribute__((ext_vector_type(8))) short short8;
typedef __attribute__((ext_vector_type(4))) float floatx4;
typedef __attribute__((ext_vector_type(4))) unsigned int uintx4;

static constexpr int kB = 64, kS = 512, kN = 2048;

// ---- workspace layout (bytes) ----
// part: [4 bg][16 r][64 cg] float — used ONLY for the final step's cross-block
//       rowsum (out[:,511] normalization). Zeroed by captured memset each launch.
// slabs: [kS][kB][kN] ushort bf16 — slab 0 = h0, slab t+1 = e_t. Write-once per
//       launch. SELF-VALIDATING: ws is poisoned 0xAA each launch -> every unwritten
//       4B word has bit31=1; every written word has bit31=0 (high bf16 is e>0 or
//       h0>=0, sign bit 0). Consumers poll their own A-fragment words with
//       cache-bypassing (sc0 sc1) loads until all sign bits clear — the poll IS the
//       load, no flags, no producer-side drain, no staleness (IC is truth).
static constexpr size_t PART_OFF   = 0;
static constexpr size_t PART_BYTES = (size_t)4 * 16 * 64 * 4;   // 16 KiB
static constexpr size_t EBUF_OFF   = 16384;                     // 4096-aligned
static constexpr size_t SLAB_ELEMS = (size_t)kB * kN;           // 131072
// total = 16384 + 512*262144 = 134,234,112 B (< previous 142.6 MB proven bound)

__device__ __forceinline__ unsigned short f2bf(float x) {
    unsigned u = __builtin_bit_cast(unsigned, x);
    u = (u + 0x7fffu + ((u >> 16) & 1u)) >> 16;   // RNE fp32 -> bf16
    return (unsigned short)u;
}

// ================== 256 blocks x 256 thr, 152 KiB LDS, 1 block/CU ==================
// Block (bg,cg): batch rows [bg*16,+16), cols [cg*32,+32). Per step critical path:
//   producer e-store (agent, write-through to IC) --> consumer's bypassing poll-load
//   sees it --> MFMA. ONE IC trip. Softmax denominator = local rowsum of the A-data
//   via a third MFMA chain against an all-ones B fragment (every block holds the
//   full 2048-wide e-rows as A fragments anyway). out[t] needs s_{t+1}: deferred
//   one iteration (e kept in 2 VGPRs). Last step uses the old part/poll round.
__global__ __launch_bounds__(256) void pcn(
    const float* __restrict__ vel, const float* __restrict__ h0,
    const float* __restrict__ Wlin, const float* __restrict__ blin,
    const float* __restrict__ Wrec, float* __restrict__ out,
    float* part, unsigned short* ebuf)
{
    extern __shared__ char smem[];
    short8* Wlds = (short8*)smem;                 // [64 kt][2 ct][64 lanes] = 128 KiB
    float*  red  = (float*)(smem + 131072);       // [2 buf][4 w][512]      =  16 KiB
    float*  red2 = (float*)(smem + 147456);       // [2 buf][4 w][256]      =   8 KiB

    const int tid  = threadIdx.x;
    const int lane = tid & 63;
    const int w    = tid >> 6;
    const int bg   = (blockIdx.x & 7) >> 1;                       // 0..3
    const int cg   = ((blockIdx.x >> 3) << 1) | (blockIdx.x & 1); // 0..63
    const int b0   = bg * 16;
    const int c0   = cg * 32;
    const int koff = (lane >> 4) << 3;  // quad*8: k-offset of this lane's A/B fragment

    const int r   = tid >> 4;        // 0..15: row in tile
    const int c16 = tid & 15;
    const int cc  = c16 * 2;         // even col in tile (2 adjacent cols/thread)

    // publish h0 -> slab 0 FIRST (agent write-through; arrival self-marked by sign bit)
    {
        const float a0 = h0[(size_t)(b0 + r) * kN + c0 + cc];
        const float a1 = h0[(size_t)(b0 + r) * kN + c0 + cc + 1];
        const unsigned pk = (unsigned)f2bf(a0) | ((unsigned)f2bf(a1) << 16);
        __hip_atomic_store((unsigned*)(ebuf + (size_t)(b0 + r) * kN + c0 + cc), pk,
                           __ATOMIC_RELAXED, __HIP_MEMORY_SCOPE_AGENT);
    }

    // ---- one-time: stage W_rec[k, c0..c0+31] into LDS, B-fragment order ----
    for (int kt = w * 16; kt < w * 16 + 16; ++kt) {
        for (int ct = 0; ct < 2; ++ct) {
            const int colg = c0 + ct * 16 + (lane & 15);
            const int kb   = kt * 32 + koff;
            short8 v;
            #pragma unroll
            for (int j = 0; j < 8; ++j)
                v[j] = (short)f2bf(Wrec[(size_t)(kb + j) * kN + colg]);
            Wlds[(kt * 2 + ct) * 64 + lane] = v;
        }
    }

    const float wl00 = Wlin[(c0 + cc) * 2 + 0],     wl01 = Wlin[(c0 + cc) * 2 + 1];
    const float wl10 = Wlin[(c0 + cc + 1) * 2 + 0], wl11 = Wlin[(c0 + cc + 1) * 2 + 1];
    const float bl0  = blin[c0 + cc], bl1 = blin[c0 + cc + 1];

    __syncthreads();   // Wlds fully staged (one-time full barrier is fine)

    short8 onesB;      // all-ones B fragment: D[r][c] = rowsum(A row r) for every c
    #pragma unroll
    for (int j = 0; j < 8; ++j) onesB[j] = (short)0x3F80;

    const int arow = b0 + (lane & 15);
    const char* const abase0 =
        (const char*)ebuf + 2 * ((size_t)arow * kN + w * 512 + koff);

    float prev_e0 = 0.f, prev_e1 = 0.f;

// issue / selective-retry of the 16 bypassing 16B poll-loads (64B chunk stride)
#define PCN_LD(i, ofs) \
    asm volatile("global_load_dwordx4 %0, %1, off offset:" #ofs " sc0 sc1" \
                 : "=v"(tmp[i]) : "v"(aptr))
#define PCN_RLD(i, ofs) \
    if (((tmp[i][0] | tmp[i][1] | tmp[i][2] | tmp[i][3]) >> 31) != 0) \
        asm volatile("global_load_dwordx4 %0, %1, off offset:" #ofs " sc0 sc1" \
                     : "=v"(tmp[i]) : "v"(aptr))

    for (int t = 0; t < kS; ++t) {
        const float2 vv = *(const float2*)(vel + ((size_t)(b0 + r) * kS + t) * 2);
        const char* aptr = abase0 + (size_t)t * (SLAB_ELEMS * 2);

        // ---- phase 1: poll-load this wave's A fragments straight from IC ----
        uintx4 tmp[16];
        PCN_LD(0, 0);    PCN_LD(1, 64);   PCN_LD(2, 128);  PCN_LD(3, 192);
        PCN_LD(4, 256);  PCN_LD(5, 320);  PCN_LD(6, 384);  PCN_LD(7, 448);
        PCN_LD(8, 512);  PCN_LD(9, 576);  PCN_LD(10, 640); PCN_LD(11, 704);
        PCN_LD(12, 768); PCN_LD(13, 832); PCN_LD(14, 896); PCN_LD(15, 960);
        asm volatile("s_waitcnt vmcnt(0)" ::: "memory");
        __builtin_amdgcn_sched_barrier(0);
        {
            int spin = 0;
            for (;;) {
                unsigned bad = 0;
                #pragma unroll
                for (int kt = 0; kt < 16; ++kt)
                    bad |= tmp[kt][0] | tmp[kt][1] | tmp[kt][2] | tmp[kt][3];
                if (__all((int)((bad >> 31) == 0))) break;
                if (++spin > 2) __builtin_amdgcn_s_sleep(1);
                PCN_RLD(0, 0);    PCN_RLD(1, 64);   PCN_RLD(2, 128);  PCN_RLD(3, 192);
                PCN_RLD(4, 256);  PCN_RLD(5, 320);  PCN_RLD(6, 384);  PCN_RLD(7, 448);
                PCN_RLD(8, 512);  PCN_RLD(9, 576);  PCN_RLD(10, 640); PCN_RLD(11, 704);
                PCN_RLD(12, 768); PCN_RLD(13, 832); PCN_RLD(14, 896); PCN_RLD(15, 960);
                asm volatile("s_waitcnt vmcnt(0)" ::: "memory");
                __builtin_amdgcn_sched_barrier(0);
            }
        }
        __builtin_amdgcn_sched_barrier(0);

        // ---- phase 2: MFMA over this wave's K-slice (+ rowsum chain) ----
        floatx4 acc0 = {0.f,0.f,0.f,0.f}, acc1 = {0.f,0.f,0.f,0.f},
                acc2 = {0.f,0.f,0.f,0.f};
        #pragma unroll
        for (int kt = 0; kt < 16; ++kt) {
            const int ktg = w * 16 + kt;
            const short8 bq0 = Wlds[(ktg * 2 + 0) * 64 + lane];
            const short8 bq1 = Wlds[(ktg * 2 + 1) * 64 + lane];
            const short8 a   = __builtin_bit_cast(short8, tmp[kt]);
            acc0 = __builtin_amdgcn_mfma_f32_16x16x32_bf16(a, bq0, acc0, 0, 0, 0);
            acc1 = __builtin_amdgcn_mfma_f32_16x16x32_bf16(a, bq1, acc1, 0, 0, 0);
            acc2 = __builtin_amdgcn_mfma_f32_16x16x32_bf16(a, onesB, acc2, 0, 0, 0);
        }

        // cross-wave K reduce via double-buffered LDS -> ONE raw barrier per step
        float* redb  = red  + (t & 1) * 2048;
        float* red2b = red2 + (t & 1) * 1024;
        {
            const int ccol = lane & 15, crow = (lane >> 4) * 4;
            #pragma unroll
            for (int i = 0; i < 4; ++i) {
                redb[w * 512 + (crow + i) * 32 + ccol]      = acc0[i];
                redb[w * 512 + (crow + i) * 32 + 16 + ccol] = acc1[i];
                red2b[w * 256 + (crow + i) * 16 + ccol]     = acc2[i];
            }
        }
        __builtin_amdgcn_sched_barrier(0);
        asm volatile("s_waitcnt lgkmcnt(0)" ::: "memory");  // LDS writes visible
        __builtin_amdgcn_s_barrier();                       // NO vmcnt drain here
        __builtin_amdgcn_sched_barrier(0);

        float g0 = 0.f, g1 = 0.f, sr = 0.f;
        {
            const int cell = tid * 2;
            #pragma unroll
            for (int ww = 0; ww < 4; ++ww) {
                g0 += redb[ww * 512 + cell];
                g1 += redb[ww * 512 + cell + 1];
                sr += red2b[ww * 256 + tid];
            }
        }
        // s_t = rowsum(slab t); slab 0 = h0 enters unnormalized (reference semantics)
        const float s_inv = (t == 0) ? 1.0f : 1.0f / sr;

        // ---- epilogue: z = base + g/s_t ; e = exp(z) ; publish slab t+1 ----
        const float z0 = fmaf(g0, s_inv, fmaf(vv.x, wl00, fmaf(vv.y, wl01, bl0)));
        const float z1 = fmaf(g1, s_inv, fmaf(vv.x, wl10, fmaf(vv.y, wl11, bl1)));
        const float e0 = __expf(z0), e1 = __expf(z1);

        if (t < kS - 1) {
            const unsigned pk = (unsigned)f2bf(e0) | ((unsigned)f2bf(e1) << 16);
            __hip_atomic_store(
                (unsigned*)(ebuf + (size_t)(t + 1) * SLAB_ELEMS + (size_t)(b0 + r) * kN + c0 + cc),
                pk, __ATOMIC_RELAXED, __HIP_MEMORY_SCOPE_AGENT);
        }
        // deferred output for step t-1: out[:,t-1] = e_prev / s_t  (plain cached)
        if (t > 0) {
            float2 o; o.x = prev_e0 * s_inv; o.y = prev_e1 * s_inv;
            *(float2*)(out + ((size_t)(b0 + r) * kS + (t - 1)) * kN + c0 + cc) = o;
        }
        prev_e0 = e0; prev_e1 = e1;
    }

    // ---- final step: cross-block rowsum of e_511 via part (old flag protocol) ----
    float es = prev_e0 + prev_e1;
    es += __shfl_xor(es, 8, 16);
    es += __shfl_xor(es, 4, 16);
    es += __shfl_xor(es, 2, 16);
    es += __shfl_xor(es, 1, 16);
    if (c16 == 0)
        __hip_atomic_store(part + ((size_t)bg * 16 + r) * 64 + cg, es,
                           __ATOMIC_RELAXED, __HIP_MEMORY_SCOPE_AGENT);
    float p0, p1, p2, p3;
    {
        const float* fpb = part + ((size_t)bg * 16 + r) * 64 + c16 * 4;
        bool rdy = false;
        int spin = 0;
        do {
            p0 = __hip_atomic_load(fpb + 0, __ATOMIC_RELAXED, __HIP_MEMORY_SCOPE_AGENT);
            p1 = __hip_atomic_load(fpb + 1, __ATOMIC_RELAXED, __HIP_MEMORY_SCOPE_AGENT);
            p2 = __hip_atomic_load(fpb + 2, __ATOMIC_RELAXED, __HIP_MEMORY_SCOPE_AGENT);
            p3 = __hip_atomic_load(fpb + 3, __ATOMIC_RELAXED, __HIP_MEMORY_SCOPE_AGENT);
            rdy = (p0 != 0.f) & (p1 != 0.f) & (p2 != 0.f) & (p3 != 0.f);
            if (++spin > 8) __builtin_amdgcn_s_sleep(1);
        } while (!__all((int)rdy));
    }
    float s = (p0 + p1) + (p2 + p3);
    s += __shfl_xor(s, 8, 16);
    s += __shfl_xor(s, 4, 16);
    s += __shfl_xor(s, 2, 16);
    s += __shfl_xor(s, 1, 16);
    const float sf = 1.0f / s;
    {
        float2 o; o.x = prev_e0 * sf; o.y = prev_e1 * sf;
        *(float2*)(out + ((size_t)(b0 + r) * kS + (kS - 1)) * kN + c0 + cc) = o;
    }
}

extern "C" void kernel_launch(void* const* d_in, const int* in_sizes, int n_in,
                              void* d_out, int out_size, void* d_ws, size_t ws_size,
                              hipStream_t stream)
{
    (void)in_sizes; (void)n_in; (void)out_size; (void)ws_size;
    const float* vel  = (const float*)d_in[0];
    const float* h0   = (const float*)d_in[1];
    const float* Wlin = (const float*)d_in[2];
    const float* blin = (const float*)d_in[3];
    const float* Wrec = (const float*)d_in[4];
    float* out = (float*)d_out;

    char* ws = (char*)d_ws;
    float* part          = (float*)(ws + PART_OFF);
    unsigned short* ebuf = (unsigned short*)(ws + EBUF_OFF);

    // final-step partials must start 0 (ws is poisoned 0xAA each launch; that
    // poison IS the slab-word "not yet written" marker — bit31 set)
    (void)hipMemsetAsync(ws + PART_OFF, 0, PART_BYTES, stream);

    const unsigned smem = 131072 + 16384 + 8192;   // 155648 B -> 1 block/CU
    (void)hipFuncSetAttribute((const void*)pcn,
        hipFuncAttributeMaxDynamicSharedMemorySize, (int)smem);

    void* args[] = { (void*)&vel, (void*)&h0, (void*)&Wlin, (void*)&blin,
                     (void*)&Wrec, (void*)&out, (void*)&part, (void*)&ebuf };
    hipError_t err = hipLaunchCooperativeKernel((const void*)pcn,
        dim3(256), dim3(256), args, smem, stream);
    if (err != hipSuccess) {
        (void)hipGetLastError();
        // plain launch: 256 blocks @ 1 block/CU are co-resident by capacity
        hipLaunchKernelGGL(pcn, dim3(256), dim3(256), smem, stream,
                           vel, h0, Wlin, blin, Wrec, out, part, ebuf);
    }
}